// Round 9
// baseline (262.158 us; speedup 1.0000x reference)
//
#include <hip/hip_runtime.h>
#include <cstdint>
#include <cstddef>

// Problem constants (fixed by reference)
#define Bb   8
#define Ss   1024
#define NXx  1024
#define Hh   16
#define HDd  64
#define Mm   (Bb*Ss)      // 8192 rows

typedef __bf16 bf16x8 __attribute__((ext_vector_type(8)));
typedef float  f32x4  __attribute__((ext_vector_type(4)));

// cheap near-RNE fp32->bf16 (2 VALU ops); accuracy headroom is ~4x vs threshold
__device__ __forceinline__ unsigned short f2bf(float f) {
    union { float f; unsigned int u; } v; v.f = f;
    return (unsigned short)((v.u + 0x8000u) >> 16);
}

// packed fp32x2 -> bf16x2 (RNE), single VOP3
__device__ __forceinline__ unsigned cvt_pk_bf16(float lo, float hi) {
    unsigned r;
    asm("v_cvt_pk_bf16_f32 %0, %1, %2" : "=v"(r) : "v"(lo), "v"(hi));
    return r;
}

// async global->LDS, 16B per lane; LDS dest = wave-uniform base + lane*16
__device__ __forceinline__ void load_lds16(const unsigned short* g, unsigned short* lds_base) {
    __builtin_amdgcn_global_load_lds(
        (const __attribute__((address_space(1))) void*)g,
        (__attribute__((address_space(3))) void*)lds_base, 16, 0, 0);
}

// ---------------- merged prep: casts + weight transposes in one dispatch ----------------
__global__ __launch_bounds__(256) void prep(
    const float* __restrict__ x, const float* __restrict__ query,
    const float* __restrict__ caw, const float* __restrict__ cpw,
    unsigned short* __restrict__ xb, unsigned short* __restrict__ qb,
    unsigned short* __restrict__ Wt, unsigned short* __restrict__ Pt)
{
    __shared__ float tile[32][33];
    const int bid = blockIdx.x;
    const int tid = threadIdx.x;

    if (bid < 16384) {
        const float* in = (bid < 8192) ? x : query;
        unsigned short* out = (bid < 8192) ? xb : qb;
        const int i = ((bid & 8191) * 256 + tid) * 4;
        const float4 v = *(const float4*)(in + i);
        unsigned long long p = (unsigned long long)f2bf(v.x)
            | ((unsigned long long)f2bf(v.y) << 16)
            | ((unsigned long long)f2bf(v.z) << 32)
            | ((unsigned long long)f2bf(v.w) << 48);
        *(unsigned long long*)(out + i) = p;
        return;
    }

    const float* in;
    unsigned short* out;
    int C, t;
    if (bid < 16384 + 3072) { in = caw; out = Wt; C = 3072; t = bid - 16384; }
    else                    { in = cpw; out = Pt; C = 1024; t = bid - 19456; }
    const int ntx = C >> 5;
    const int c0 = (t % ntx) * 32, r0 = (t / ntx) * 32;
    const int tx = tid & 31, ty = tid >> 5;
    for (int i = ty; i < 32; i += 8)
        tile[i][tx] = in[(size_t)(r0 + i) * C + c0 + tx];
    __syncthreads();
    for (int i = ty; i < 32; i += 8)
        out[(size_t)(c0 + i) * 1024 + r0 + tx] = f2bf(tile[tx][i]);
}

// ---------------- 256x128-tile QKV GEMM: BK=32, 72KB triple-buffer, 2 blocks/CU ----------------
// r4-verified config (64.5us, VGPR 60, no spill). Do NOT raise min-waves past 4
// (r5: (512,6) capped VGPR at 85 -> acc spilled to scratch, FETCH 51->898MB, 531us).
// r9: SINGLE barrier per K-tile. With a 3-buffer ring the barA/barB pair is
// redundant: at barrier_t every wave's tile-t staging is retired (own vmcnt ran
// pre-barrier) and every wave's iter-(t-1) reads are retired (frags consumed by
// MFMAs before the barrier). Staging issued after barrier_t targets buf (t+2)%3,
// last read at iter t-1 -> covered. vmcnt(3) at iter end retires exactly tile
// t+1's 3 loads; never drains to 0 mid-loop.
__global__ __launch_bounds__(512, 4) void gemm256(
    const unsigned short* __restrict__ Ax,
    const unsigned short* __restrict__ Aq,
    const unsigned short* __restrict__ Bt,
    const float* __restrict__ bias,
    unsigned short* __restrict__ out_q,
    unsigned short* __restrict__ out_k,
    unsigned short* __restrict__ out_v)
{
    __shared__ unsigned short lds[36864];   // 72 KB: 3 x (A[256][32]=16KB | B[128][32]=8KB)

    const int tid  = threadIdx.x;
    const int w    = tid >> 6;
    const int lane = tid & 63;
    const int wm   = (w >> 1) * 64;         // 4 M-waves x 64 rows
    const int wn   = (w & 1) * 64;          // 2 N-waves x 64 cols
    const int lrow = lane & 15;
    const int quad = lane >> 4;
    const int ph   = (quad ^ (lrow & 3) ^ (lrow >> 2)) & 3;   // frag-read phys chunk

    // XCD swizzle, ni-fast within XCD: A panel reused by 12 blocks via L2
    const int n    = blockIdx.x;
    const int xcd  = n & 7;
    const int sg   = n >> 3;                     // 0..95
    const int mi   = (xcd >> 1) * 8 + sg / 12;   // 0..31
    const int ni   = (xcd & 1) * 12 + sg % 12;   // 0..23
    const int m0   = mi << 8;
    const int n0   = ni << 7;
    const int region = n0 >> 10;            // 0=Q 1=K 2=V (block-uniform, BN=128)
    const unsigned short* A = (region == 0) ? Aq : Ax;

    // staging: one load_lds16 = 16 rows x 32 cols (1KB). lane l -> row l>>2, phys l&3;
    // source logical chunk = (l&3) ^ ((l>>2)&3) ^ ((l>>4)&3)
    const int srow = lane >> 2;                  // 0..15
    const int scol = (((lane & 3) ^ (srow & 3) ^ ((srow >> 2) & 3)) << 3);
    const unsigned short* pA0 = A  + (size_t)(m0 + w * 32 + srow) * 1024 + scol;
    const unsigned short* pA1 = A  + (size_t)(m0 + w * 32 + 16 + srow) * 1024 + scol;
    const unsigned short* pB0 = Bt + (size_t)(n0 + w * 16 + srow) * 1024 + scol;

    f32x4 acc[4][4] = {};

    // prologue: stage tiles 0,1 into bufs 0,1 (6 loads in flight)
#pragma unroll
    for (int p = 0; p < 2; ++p) {
        const int bb = p * 12288;
        load_lds16(pA0, lds + bb + w * 1024);
        load_lds16(pA1, lds + bb + w * 1024 + 512);
        load_lds16(pB0, lds + bb + 8192 + w * 512);
        pA0 += 32; pA1 += 32; pB0 += 32;
    }
    asm volatile("s_waitcnt vmcnt(3)" ::: "memory");   // tile 0 staged (own)

    int cbuf = 0;   // buffer holding tile t
    int sbuf = 2;   // buffer to stage tile t+2 into
#pragma unroll 1
    for (int t = 0; t < 32; ++t) {
        __builtin_amdgcn_s_barrier();   // all: tile-t staged; reads(t-1) retired
        asm volatile("" ::: "memory");
        if (t <= 29) {                  // stage tile t+2
            const int bb = sbuf * 12288;
            load_lds16(pA0, lds + bb + w * 1024);
            load_lds16(pA1, lds + bb + w * 1024 + 512);
            load_lds16(pB0, lds + bb + 8192 + w * 512);
            pA0 += 32; pA1 += 32; pB0 += 32;
        }

        const int rA = cbuf * 12288 + (wm + lrow) * 32 + ph * 8;
        const int rB = cbuf * 12288 + 8192 + (wn + lrow) * 32 + ph * 8;
        bf16x8 af[4], bq[4];
#pragma unroll
        for (int i = 0; i < 4; ++i) af[i] = *(const bf16x8*)&lds[rA + i * 512];
#pragma unroll
        for (int j = 0; j < 4; ++j) bq[j] = *(const bf16x8*)&lds[rB + j * 512];
        // no barrier: compiler's own-wave lgkmcnt gates each MFMA; waves skew
        __builtin_amdgcn_s_setprio(1);
#pragma unroll
        for (int i = 0; i < 4; ++i)
#pragma unroll
            for (int j = 0; j < 4; ++j)
                acc[i][j] = __builtin_amdgcn_mfma_f32_16x16x32_bf16(af[i], bq[j], acc[i][j], 0, 0, 0);
        __builtin_amdgcn_s_setprio(0);

        // retire tile t+1's staging before next barrier (never drain mid-loop)
        if (t <= 29)      asm volatile("s_waitcnt vmcnt(3)" ::: "memory");
        else if (t == 30) asm volatile("s_waitcnt vmcnt(0)" ::: "memory");

        cbuf = (cbuf == 2) ? 0 : cbuf + 1;
        sbuf = (sbuf == 2) ? 0 : sbuf + 1;
    }

    __syncthreads();   // full drain; safe to reuse LDS for epilogue bounce

    unsigned short* ep = lds + w * 2048;     // per-wave 4 KB bounce region

    if (region != 2) {
        unsigned short* outp = (region == 0) ? out_q : out_k;
        const float sc = (region == 0) ? 0.125f : 1.0f;   // fold 1/sqrt(64) into Q
#pragma unroll
        for (int j = 0; j < 4; ++j) {
            const float bv = bias[n0 + wn + j * 16 + lrow];
#pragma unroll
            for (int i = 0; i < 4; ++i)
#pragma unroll
                for (int r = 0; r < 4; ++r)
                    ep[(i * 16 + quad * 4 + r) * 24 + lrow] = f2bf((acc[i][j][r] + bv) * sc);
            // per-wave region: in-wave LDS ordering, no barrier needed
#pragma unroll
            for (int tt = 0; tt < 2; ++tt) {
                const int c    = tt * 64 + lane;
                const int row  = c >> 1, ch = (c & 1) * 8;
                const int mrow = m0 + wm + row;
                const int cc   = (n0 + wn + j * 16 + ch) & (NXx - 1);
                const int hh   = cc >> 6, dd = cc & 63;
                const int bh   = (mrow >> 10) * Hh + hh;
                const int ss   = mrow & (Ss - 1);
                *(uint4*)&outp[((size_t)bh * Ss + ss) * HDd + dd] =
                    *(const uint4*)&ep[row * 24 + ch];
            }
        }
    } else {
        // V: bounce transposed [col][row] (stride 72) for contiguous-s wide stores
#pragma unroll
        for (int j = 0; j < 4; ++j) {
            const float bv = bias[n0 + wn + j * 16 + lrow];
#pragma unroll
            for (int i = 0; i < 4; ++i)
#pragma unroll
                for (int r = 0; r < 4; ++r)
                    ep[lrow * 72 + i * 16 + quad * 4 + r] = f2bf(acc[i][j][r] + bv);
#pragma unroll
            for (int tt = 0; tt < 2; ++tt) {
                const int c    = tt * 64 + lane;
                const int col  = c >> 3, rc = (c & 7) * 8;
                const int cc   = (n0 + wn + j * 16 + col) & (NXx - 1);
                const int hh   = cc >> 6, dd = cc & 63;
                const int mrow = m0 + wm + rc;
                const int bh   = (mrow >> 10) * Hh + hh;
                const int ss   = mrow & (Ss - 1);
                *(uint4*)&out_v[((size_t)bh * HDd + dd) * Ss + ss] =
                    *(const uint4*)&ep[col * 72 + rc];
            }
        }
    }
}

// ---------------- output projection: 128x128 tile, BK=32, 48KB triple-buffer ----------------
// 512 blocks = exact 2/CU resident (r6 showed 1 block/CU proj loses the supply-rate
// concurrency; gemm128's win was 2-3 blocks/CU). Same single-barrier 3-buffer ring
// as gemm256; per-wave 2 loads/tile -> vmcnt(2) steady. Direct fp32 epilogue
// (verified mode-1 index algebra).
__global__ __launch_bounds__(512, 4) void gemmp(
    const unsigned short* __restrict__ A,    // about [8192][1024] bf16
    const unsigned short* __restrict__ Bt,   // Pt [1024][1024] (row = out col)
    const float* __restrict__ bias,
    float* __restrict__ out_f)
{
    __shared__ unsigned short lds[24576];   // 48 KB: 3 x (A[128][32]=8KB | B[128][32]=8KB)

    const int tid  = threadIdx.x;
    const int w    = tid >> 6;
    const int lane = tid & 63;
    const int wm   = (w >> 1) * 32;         // 4 M-waves x 32 rows
    const int wn   = (w & 1) * 64;          // 2 N-waves x 64 cols
    const int lrow = lane & 15;
    const int quad = lane >> 4;
    const int ph   = (quad ^ (lrow & 3) ^ (lrow >> 2)) & 3;

    // 512 = 8 XCD x 64; per XCD-half 16(mi) x 4(ni), ni-fast for A-panel L2 reuse
    const int n    = blockIdx.x;
    const int xcd  = n & 7;
    const int sg   = n >> 3;                     // 0..63
    const int mi   = (xcd >> 1) * 16 + sg / 4;   // 0..63
    const int ni   = (xcd & 1) * 4 + (sg & 3);   // 0..7
    const int m0   = mi << 7;
    const int n0   = ni << 7;

    const int srow = lane >> 2;
    const int scol = (((lane & 3) ^ (srow & 3) ^ ((srow >> 2) & 3)) << 3);
    const unsigned short* pA0 = A  + (size_t)(m0 + w * 16 + srow) * 1024 + scol;
    const unsigned short* pB0 = Bt + (size_t)(n0 + w * 16 + srow) * 1024 + scol;

    f32x4 acc[2][4] = {};

    // prologue: stage tiles 0,1 into bufs 0,1 (4 loads in flight)
#pragma unroll
    for (int p = 0; p < 2; ++p) {
        const int bb = p * 8192;
        load_lds16(pA0, lds + bb + w * 512);
        load_lds16(pB0, lds + bb + 4096 + w * 512);
        pA0 += 32; pB0 += 32;
    }
    asm volatile("s_waitcnt vmcnt(2)" ::: "memory");   // tile 0 staged (own)

    int cbuf = 0, sbuf = 2;
#pragma unroll 1
    for (int t = 0; t < 32; ++t) {
        __builtin_amdgcn_s_barrier();
        asm volatile("" ::: "memory");
        if (t <= 29) {
            const int bb = sbuf * 8192;
            load_lds16(pA0, lds + bb + w * 512);
            load_lds16(pB0, lds + bb + 4096 + w * 512);
            pA0 += 32; pB0 += 32;
        }

        const int rA = cbuf * 8192 + (wm + lrow) * 32 + ph * 8;
        const int rB = cbuf * 8192 + 4096 + (wn + lrow) * 32 + ph * 8;
        bf16x8 af[2], bq[4];
#pragma unroll
        for (int i = 0; i < 2; ++i) af[i] = *(const bf16x8*)&lds[rA + i * 512];
#pragma unroll
        for (int j = 0; j < 4; ++j) bq[j] = *(const bf16x8*)&lds[rB + j * 512];
        __builtin_amdgcn_s_setprio(1);
#pragma unroll
        for (int i = 0; i < 2; ++i)
#pragma unroll
            for (int j = 0; j < 4; ++j)
                acc[i][j] = __builtin_amdgcn_mfma_f32_16x16x32_bf16(af[i], bq[j], acc[i][j], 0, 0, 0);
        __builtin_amdgcn_s_setprio(0);

        if (t <= 29)      asm volatile("s_waitcnt vmcnt(2)" ::: "memory");
        else if (t == 30) asm volatile("s_waitcnt vmcnt(0)" ::: "memory");

        cbuf = (cbuf == 2) ? 0 : cbuf + 1;
        sbuf = (sbuf == 2) ? 0 : sbuf + 1;
    }

    // direct fp32 epilogue (verified algebra)
#pragma unroll
    for (int i = 0; i < 2; ++i)
#pragma unroll
        for (int j = 0; j < 4; ++j) {
            const int ncol = n0 + wn + j * 16 + lrow;
            const float bv = bias[ncol];
#pragma unroll
            for (int r = 0; r < 4; ++r) {
                const int mrow = m0 + wm + i * 16 + quad * 4 + r;
                out_f[(size_t)mrow * NXx + ncol] = acc[i][j][r] + bv;
            }
        }
}

// ---------------- flash-style causal attention, S^T, 8-wave 256-row supertiles ----------------
// r7 structure + r8 VALU diet + r9 single-barrier ring (same derivation as gemm256;
// per-wave 2 loads/iter -> vmcnt(2) steady / 0 at it==18). Transition's aq reloads
// and output stores only make counted waits over-wait (monotone-safe).
__global__ __launch_bounds__(512) void flash_attn(
    const unsigned short* __restrict__ Qh,
    const unsigned short* __restrict__ Kh,
    const unsigned short* __restrict__ Vt,
    unsigned short* __restrict__ about)
{
    __shared__ unsigned short Ks[3][64][64];     // phys_chunk = log ^ (row&7)
    __shared__ unsigned short Vs[3][64][64];
    __shared__ unsigned short Pl[8][32][72];     // per-wave P, [q][key], stride 144B

    const int tid  = threadIdx.x;
    const int w    = tid >> 6;                   // 0..7
    const int lane = tid & 63;
    const int bh   = blockIdx.x & 127;
    const int prg  = blockIdx.x >> 7;            // 0 -> (st 0,3), 1 -> (st 1,2)
    const int b    = bh >> 4, h = bh & 15;
    const int lrow = lane & 15;
    const int quad = lane >> 4;

    const unsigned short* Qb = Qh + (size_t)bh * Ss * HDd;
    const unsigned short* Kb = Kh + (size_t)bh * Ss * HDd;
    const unsigned short* Vb = Vt + (size_t)bh * HDd * Ss;

    const int sr = lane >> 3;
    const int lc = (((lane & 7) ^ sr) << 3);

    const int swz = lrow & 7;
    const int ca = ((quad ^ swz) << 3);            // k/d 0..31
    const int cb = (((4 + quad) ^ swz) << 3);      // k/d 32..63

    const int nkt0 = 4 * prg + 4;                  // half-A iters; total = 20
    int qw = prg * 256 + w * 32;                   // wave's first q row

    bf16x8 aq[2][2];
#pragma unroll
    for (int g = 0; g < 2; ++g)
#pragma unroll
        for (int c = 0; c < 2; ++c)
            aq[g][c] = *(const bf16x8*)(Qb + (size_t)(qw + g * 16 + lrow) * HDd + c * 32 + quad * 8);

    f32x4 O[2][4] = {};
    float lsum[2] = { 0.f, 0.f };

    // prologue: stage iters 0,1 into bufs 0,1
#pragma unroll
    for (int p = 0; p < 2; ++p) {
        load_lds16(Kb + (size_t)(p * 64 + w * 8 + sr) * HDd + lc, &Ks[p][w * 8][0]);
        load_lds16(Vb + (size_t)(w * 8 + sr) * Ss + p * 64 + lc,  &Vs[p][w * 8][0]);
    }
    asm volatile("s_waitcnt vmcnt(2)" ::: "memory");   // iter 0 staged (own)

    int cbuf = 0, sbuf = 2;
#pragma unroll 1
    for (int it = 0; it < 20; ++it) {
        __builtin_amdgcn_s_barrier();   // all: iter-it staged; reads(it-1) retired
        asm volatile("" ::: "memory");
        if (it <= 17) {                 // stage iter it+2
            const int itn = it + 2;
            const int k0n = (itn >= nkt0 ? itn - nkt0 : itn) * 64;
            load_lds16(Kb + (size_t)(k0n + w * 8 + sr) * HDd + lc, &Ks[sbuf][w * 8][0]);
            load_lds16(Vb + (size_t)(w * 8 + sr) * Ss + k0n + lc,  &Vs[sbuf][w * 8][0]);
        }

        if (it == nkt0) {
            // finish half A: quad-reduce l, normalize, store (registers + shfl only)
#pragma unroll
            for (int g = 0; g < 2; ++g) {
                float l = lsum[g];
                l += __shfl_xor(l, 16);
                l += __shfl_xor(l, 32);
                const float inv = 1.0f / l;
#pragma unroll
                for (int r = 0; r < 4; ++r) {
                    const float invr = __shfl(inv, quad * 4 + r);
                    const int q = qw + g * 16 + quad * 4 + r;
                    const size_t base = ((size_t)b * Ss + q) * NXx + h * HDd;
#pragma unroll
                    for (int f = 0; f < 4; ++f)
                        about[base + f * 16 + lrow] = f2bf(O[g][f][r] * invr);
                }
            }
            // switch to half B (supertile 3-prg)
            qw = (3 - prg) * 256 + w * 32;
#pragma unroll
            for (int g = 0; g < 2; ++g)
#pragma unroll
                for (int c = 0; c < 2; ++c)
                    aq[g][c] = *(const bf16x8*)(Qb + (size_t)(qw + g * 16 + lrow) * HDd + c * 32 + quad * 8);
#pragma unroll
            for (int g = 0; g < 2; ++g) {
                lsum[g] = 0.f;
#pragma unroll
                for (int f = 0; f < 4; ++f) O[g][f] = (f32x4){0.f, 0.f, 0.f, 0.f};
            }
        }

        const int k0 = (it >= nkt0 ? it - nkt0 : it) * 64;
        if (k0 <= qw + 31) {                   // else fully masked (wave-uniform)
            // S^T = K·Q^T: D[key = j*16+quad*4+r][q = g*16+lrow]
            f32x4 st[2][4] = {};
#pragma unroll
            for (int j = 0; j < 4; ++j) {
                const bf16x8 kf0 = *(const bf16x8*)&Ks[cbuf][j * 16 + lrow][ca];
                const bf16x8 kf1 = *(const bf16x8*)&Ks[cbuf][j * 16 + lrow][cb];
                st[0][j] = __builtin_amdgcn_mfma_f32_16x16x32_bf16(kf0, aq[0][0], st[0][j], 0, 0, 0);
                st[0][j] = __builtin_amdgcn_mfma_f32_16x16x32_bf16(kf1, aq[0][1], st[0][j], 0, 0, 0);
                st[1][j] = __builtin_amdgcn_mfma_f32_16x16x32_bf16(kf0, aq[1][0], st[1][j], 0, 0, 0);
                st[1][j] = __builtin_amdgcn_mfma_f32_16x16x32_bf16(kf1, aq[1][1], st[1][j], 0, 0, 0);
            }

            const bool needMask = (k0 + 63 > qw);  // wave-uniform
#pragma unroll
            for (int g = 0; g < 2; ++g) {
                const int qg = qw + g * 16 + lrow;  // this lane's q row
#pragma unroll
                for (int j = 0; j < 4; ++j) {
                    const int kbase = k0 + j * 16 + quad * 4;
                    float e0 = __expf(st[g][j][0]);   // Qh pre-scaled by 0.125
                    float e1 = __expf(st[g][j][1]);
                    float e2 = __expf(st[g][j][2]);
                    float e3 = __expf(st[g][j][3]);
                    if (needMask) {
                        if (kbase     > qg) e0 = 0.f;
                        if (kbase + 1 > qg) e1 = 0.f;
                        if (kbase + 2 > qg) e2 = 0.f;
                        if (kbase + 3 > qg) e3 = 0.f;
                    }
                    lsum[g] += (e0 + e1) + (e2 + e3);
                    uint2 pk;
                    pk.x = cvt_pk_bf16(e0, e1);
                    pk.y = cvt_pk_bf16(e2, e3);
                    *(uint2*)&Pl[w][g * 16 + lrow][j * 16 + quad * 4] = pk;
                }
            }
            // Pl[w] is per-wave: in-wave DS ordering suffices, no barrier

            bf16x8 ap[2][2];
#pragma unroll
            for (int g = 0; g < 2; ++g)
#pragma unroll
                for (int c = 0; c < 2; ++c)
                    ap[g][c] = *(const bf16x8*)&Pl[w][g * 16 + lrow][c * 32 + quad * 8];
#pragma unroll
            for (int f = 0; f < 4; ++f) {
                const bf16x8 vf0 = *(const bf16x8*)&Vs[cbuf][f * 16 + lrow][ca];
                const bf16x8 vf1 = *(const bf16x8*)&Vs[cbuf][f * 16 + lrow][cb];
                O[0][f] = __builtin_amdgcn_mfma_f32_16x16x32_bf16(ap[0][0], vf0, O[0][f], 0, 0, 0);
                O[0][f] = __builtin_amdgcn_mfma_f32_16x16x32_bf16(ap[0][1], vf1, O[0][f], 0, 0, 0);
                O[1][f] = __builtin_amdgcn_mfma_f32_16x16x32_bf16(ap[1][0], vf0, O[1][f], 0, 0, 0);
                O[1][f] = __builtin_amdgcn_mfma_f32_16x16x32_bf16(ap[1][1], vf1, O[1][f], 0, 0, 0);
            }
        }

        // retire iter it+1's staging before next barrier (outside the masked skip)
        if (it <= 17)      asm volatile("s_waitcnt vmcnt(2)" ::: "memory");
        else if (it == 18) asm volatile("s_waitcnt vmcnt(0)" ::: "memory");

        cbuf = (cbuf == 2) ? 0 : cbuf + 1;
        sbuf = (sbuf == 2) ? 0 : sbuf + 1;
    }

    // final epilogue: half B
#pragma unroll
    for (int g = 0; g < 2; ++g) {
        float l = lsum[g];
        l += __shfl_xor(l, 16);
        l += __shfl_xor(l, 32);
        const float inv = 1.0f / l;
#pragma unroll
        for (int r = 0; r < 4; ++r) {
            const float invr = __shfl(inv, quad * 4 + r);
            const int q = qw + g * 16 + quad * 4 + r;
            const size_t base = ((size_t)b * Ss + q) * NXx + h * HDd;
#pragma unroll
            for (int f = 0; f < 4; ++f)
                about[base + f * 16 + lrow] = f2bf(O[g][f][r] * invr);
        }
    }
}

// ---------------- launch ----------------
extern "C" void kernel_launch(void* const* d_in, const int* in_sizes, int n_in,
                              void* d_out, int out_size, void* d_ws, size_t ws_size,
                              hipStream_t stream) {
    const float* x        = (const float*)d_in[0];
    const float* query    = (const float*)d_in[1];
    const float* c_attn_w = (const float*)d_in[2];
    const float* c_attn_b = (const float*)d_in[3];
    const float* c_proj_w = (const float*)d_in[4];
    const float* c_proj_b = (const float*)d_in[5];
    float* out = (float*)d_out;

    const size_t nTok = (size_t)Mm * NXx;          // 8388608
    char* ws = (char*)d_ws;
    unsigned short* xb    = (unsigned short*)ws;                 ws += nTok * 2;
    unsigned short* qb    = (unsigned short*)ws;                 ws += nTok * 2;
    unsigned short* Wt    = (unsigned short*)ws;                 ws += (size_t)3 * NXx * NXx * 2;  // [3072][1024]
    unsigned short* Pt    = (unsigned short*)ws;                 ws += (size_t)NXx * NXx * 2;      // [1024][1024]
    unsigned short* Qh    = (unsigned short*)ws;                 ws += nTok * 2;
    unsigned short* Kh    = (unsigned short*)ws;                 ws += nTok * 2;
    unsigned short* Vt    = (unsigned short*)ws;                 ws += nTok * 2;
    unsigned short* about = (unsigned short*)ws;                 ws += nTok * 2;
    if ((size_t)(ws - (char*)d_ws) > ws_size) return;

    // merged prep: casts + transposes
    prep<<<20480, 256, 0, stream>>>(x, query, c_attn_w, c_proj_w, xb, qb, Wt, Pt);

    // QKV: M=8192, N=3072, K=1024 — 256x128 tiles, BK=32, single-barrier ring
    gemm256<<<768, 512, 0, stream>>>(xb, qb, Wt, c_attn_b, Qh, Kh, Vt);

    // causal flash attention (8-wave supertile pairs; single-barrier ring)
    flash_attn<<<256, 512, 0, stream>>>(Qh, Kh, Vt, about);

    // output projection: M=8192, N=1024, K=1024 — 128x128 BK=32 pipelined, 2/CU
    gemmp<<<512, 512, 0, stream>>>(about, Pt, c_proj_b, out);
}

// Round 10
// 252.216 us; speedup vs baseline: 1.0394x; 1.0394x over previous
//
#include <hip/hip_runtime.h>
#include <cstdint>
#include <cstddef>

// Problem constants (fixed by reference)
#define Bb   8
#define Ss   1024
#define NXx  1024
#define Hh   16
#define HDd  64
#define Mm   (Bb*Ss)      // 8192 rows

typedef __bf16 bf16x8 __attribute__((ext_vector_type(8)));
typedef float  f32x4  __attribute__((ext_vector_type(4)));

// cheap near-RNE fp32->bf16 (2 VALU ops); accuracy headroom is ~4x vs threshold
__device__ __forceinline__ unsigned short f2bf(float f) {
    union { float f; unsigned int u; } v; v.f = f;
    return (unsigned short)((v.u + 0x8000u) >> 16);
}

// packed fp32x2 -> bf16x2 (RNE), single VOP3
__device__ __forceinline__ unsigned cvt_pk_bf16(float lo, float hi) {
    unsigned r;
    asm("v_cvt_pk_bf16_f32 %0, %1, %2" : "=v"(r) : "v"(lo), "v"(hi));
    return r;
}

// async global->LDS, 16B per lane; LDS dest = wave-uniform base + lane*16
__device__ __forceinline__ void load_lds16(const unsigned short* g, unsigned short* lds_base) {
    __builtin_amdgcn_global_load_lds(
        (const __attribute__((address_space(1))) void*)g,
        (__attribute__((address_space(3))) void*)lds_base, 16, 0, 0);
}

// ---------------- merged prep: casts + weight transposes in one dispatch ----------------
__global__ __launch_bounds__(256) void prep(
    const float* __restrict__ x, const float* __restrict__ query,
    const float* __restrict__ caw, const float* __restrict__ cpw,
    unsigned short* __restrict__ xb, unsigned short* __restrict__ qb,
    unsigned short* __restrict__ Wt, unsigned short* __restrict__ Pt)
{
    __shared__ float tile[32][33];
    const int bid = blockIdx.x;
    const int tid = threadIdx.x;

    if (bid < 16384) {
        const float* in = (bid < 8192) ? x : query;
        unsigned short* out = (bid < 8192) ? xb : qb;
        const int i = ((bid & 8191) * 256 + tid) * 4;
        const float4 v = *(const float4*)(in + i);
        unsigned long long p = (unsigned long long)f2bf(v.x)
            | ((unsigned long long)f2bf(v.y) << 16)
            | ((unsigned long long)f2bf(v.z) << 32)
            | ((unsigned long long)f2bf(v.w) << 48);
        *(unsigned long long*)(out + i) = p;
        return;
    }

    const float* in;
    unsigned short* out;
    int C, t;
    if (bid < 16384 + 3072) { in = caw; out = Wt; C = 3072; t = bid - 16384; }
    else                    { in = cpw; out = Pt; C = 1024; t = bid - 19456; }
    const int ntx = C >> 5;
    const int c0 = (t % ntx) * 32, r0 = (t / ntx) * 32;
    const int tx = tid & 31, ty = tid >> 5;
    for (int i = ty; i < 32; i += 8)
        tile[i][tx] = in[(size_t)(r0 + i) * C + c0 + tx];
    __syncthreads();
    for (int i = ty; i < 32; i += 8)
        out[(size_t)(c0 + i) * 1024 + r0 + tx] = f2bf(tile[tx][i]);
}

// ---------------- 256x128-tile QKV GEMM: BK=32, 72KB triple-buffer, 2 blocks/CU ----------------
// r9-measured best QKV (63.2us): single barrier per K-tile with 3-buffer ring.
// At barrier_t every wave's tile-t staging retired (own vmcnt pre-barrier) and
// reads(t-1) retired (MFMAs consumed frags before barrier). Staging after barrier_t
// targets buf (t+2)%3, last read at iter t-1 -> covered. vmcnt(3) at iter end
// retires exactly tile t+1's loads; never drains mid-loop.
// Do NOT raise min-waves past 4 (r5: (512,6) spilled acc, FETCH 51->898MB, 531us).
__global__ __launch_bounds__(512, 4) void gemm256(
    const unsigned short* __restrict__ Ax,
    const unsigned short* __restrict__ Aq,
    const unsigned short* __restrict__ Bt,
    const float* __restrict__ bias,
    unsigned short* __restrict__ out_q,
    unsigned short* __restrict__ out_k,
    unsigned short* __restrict__ out_v)
{
    __shared__ unsigned short lds[36864];   // 72 KB: 3 x (A[256][32]=16KB | B[128][32]=8KB)

    const int tid  = threadIdx.x;
    const int w    = tid >> 6;
    const int lane = tid & 63;
    const int wm   = (w >> 1) * 64;         // 4 M-waves x 64 rows
    const int wn   = (w & 1) * 64;          // 2 N-waves x 64 cols
    const int lrow = lane & 15;
    const int quad = lane >> 4;
    const int ph   = (quad ^ (lrow & 3) ^ (lrow >> 2)) & 3;   // frag-read phys chunk

    // XCD swizzle, ni-fast within XCD: A panel reused by 12 blocks via L2
    const int n    = blockIdx.x;
    const int xcd  = n & 7;
    const int sg   = n >> 3;                     // 0..95
    const int mi   = (xcd >> 1) * 8 + sg / 12;   // 0..31
    const int ni   = (xcd & 1) * 12 + sg % 12;   // 0..23
    const int m0   = mi << 8;
    const int n0   = ni << 7;
    const int region = n0 >> 10;            // 0=Q 1=K 2=V (block-uniform, BN=128)
    const unsigned short* A = (region == 0) ? Aq : Ax;

    // staging: one load_lds16 = 16 rows x 32 cols (1KB). lane l -> row l>>2, phys l&3;
    // source logical chunk = (l&3) ^ ((l>>2)&3) ^ ((l>>4)&3)
    const int srow = lane >> 2;                  // 0..15
    const int scol = (((lane & 3) ^ (srow & 3) ^ ((srow >> 2) & 3)) << 3);
    const unsigned short* pA0 = A  + (size_t)(m0 + w * 32 + srow) * 1024 + scol;
    const unsigned short* pA1 = A  + (size_t)(m0 + w * 32 + 16 + srow) * 1024 + scol;
    const unsigned short* pB0 = Bt + (size_t)(n0 + w * 16 + srow) * 1024 + scol;

    f32x4 acc[4][4] = {};

    // prologue: stage tiles 0,1 into bufs 0,1 (6 loads in flight)
#pragma unroll
    for (int p = 0; p < 2; ++p) {
        const int bb = p * 12288;
        load_lds16(pA0, lds + bb + w * 1024);
        load_lds16(pA1, lds + bb + w * 1024 + 512);
        load_lds16(pB0, lds + bb + 8192 + w * 512);
        pA0 += 32; pA1 += 32; pB0 += 32;
    }
    asm volatile("s_waitcnt vmcnt(3)" ::: "memory");   // tile 0 staged (own)

    int cbuf = 0;   // buffer holding tile t
    int sbuf = 2;   // buffer to stage tile t+2 into
#pragma unroll 1
    for (int t = 0; t < 32; ++t) {
        __builtin_amdgcn_s_barrier();   // all: tile-t staged; reads(t-1) retired
        asm volatile("" ::: "memory");
        if (t <= 29) {                  // stage tile t+2
            const int bb = sbuf * 12288;
            load_lds16(pA0, lds + bb + w * 1024);
            load_lds16(pA1, lds + bb + w * 1024 + 512);
            load_lds16(pB0, lds + bb + 8192 + w * 512);
            pA0 += 32; pA1 += 32; pB0 += 32;
        }

        const int rA = cbuf * 12288 + (wm + lrow) * 32 + ph * 8;
        const int rB = cbuf * 12288 + 8192 + (wn + lrow) * 32 + ph * 8;
        bf16x8 af[4], bq[4];
#pragma unroll
        for (int i = 0; i < 4; ++i) af[i] = *(const bf16x8*)&lds[rA + i * 512];
#pragma unroll
        for (int j = 0; j < 4; ++j) bq[j] = *(const bf16x8*)&lds[rB + j * 512];
        // no barrier: compiler's own-wave lgkmcnt gates each MFMA; waves skew
        __builtin_amdgcn_s_setprio(1);
#pragma unroll
        for (int i = 0; i < 4; ++i)
#pragma unroll
            for (int j = 0; j < 4; ++j)
                acc[i][j] = __builtin_amdgcn_mfma_f32_16x16x32_bf16(af[i], bq[j], acc[i][j], 0, 0, 0);
        __builtin_amdgcn_s_setprio(0);

        // retire tile t+1's staging before next barrier (never drain mid-loop)
        if (t <= 29)      asm volatile("s_waitcnt vmcnt(3)" ::: "memory");
        else if (t == 30) asm volatile("s_waitcnt vmcnt(0)" ::: "memory");

        cbuf = (cbuf == 2) ? 0 : cbuf + 1;
        sbuf = (sbuf == 2) ? 0 : sbuf + 1;
    }

    __syncthreads();   // full drain; safe to reuse LDS for epilogue bounce

    unsigned short* ep = lds + w * 2048;     // per-wave 4 KB bounce region

    if (region != 2) {
        unsigned short* outp = (region == 0) ? out_q : out_k;
        const float sc = (region == 0) ? 0.125f : 1.0f;   // fold 1/sqrt(64) into Q
#pragma unroll
        for (int j = 0; j < 4; ++j) {
            const float bv = bias[n0 + wn + j * 16 + lrow];
#pragma unroll
            for (int i = 0; i < 4; ++i)
#pragma unroll
                for (int r = 0; r < 4; ++r)
                    ep[(i * 16 + quad * 4 + r) * 24 + lrow] = f2bf((acc[i][j][r] + bv) * sc);
            // per-wave region: in-wave LDS ordering, no barrier needed
#pragma unroll
            for (int tt = 0; tt < 2; ++tt) {
                const int c    = tt * 64 + lane;
                const int row  = c >> 1, ch = (c & 1) * 8;
                const int mrow = m0 + wm + row;
                const int cc   = (n0 + wn + j * 16 + ch) & (NXx - 1);
                const int hh   = cc >> 6, dd = cc & 63;
                const int bh   = (mrow >> 10) * Hh + hh;
                const int ss   = mrow & (Ss - 1);
                *(uint4*)&outp[((size_t)bh * Ss + ss) * HDd + dd] =
                    *(const uint4*)&ep[row * 24 + ch];
            }
        }
    } else {
        // V: bounce transposed [col][row] (stride 72) for contiguous-s wide stores
#pragma unroll
        for (int j = 0; j < 4; ++j) {
            const float bv = bias[n0 + wn + j * 16 + lrow];
#pragma unroll
            for (int i = 0; i < 4; ++i)
#pragma unroll
                for (int r = 0; r < 4; ++r)
                    ep[lrow * 72 + i * 16 + quad * 4 + r] = f2bf(acc[i][j][r] + bv);
#pragma unroll
            for (int tt = 0; tt < 2; ++tt) {
                const int c    = tt * 64 + lane;
                const int col  = c >> 3, rc = (c & 7) * 8;
                const int cc   = (n0 + wn + j * 16 + col) & (NXx - 1);
                const int hh   = cc >> 6, dd = cc & 63;
                const int mrow = m0 + wm + rc;
                const int bh   = (mrow >> 10) * Hh + hh;
                const int ss   = mrow & (Ss - 1);
                *(uint4*)&out_v[((size_t)bh * HDd + dd) * Ss + ss] =
                    *(const uint4*)&ep[col * 72 + rc];
            }
        }
    }
}

// ---------------- output projection: 128x128 tile, BK=64 (r8-measured structure) ----------------
// The r9 BK=32 proj (gemmp) regressed ~6-8us: only 8 MFMAs/wave per barrier ->
// barrier/LDS overhead per MFMA ~4x worse. This is the r8 gemm128 mode-1 path
// verbatim (32 MFMAs per 2 barriers), stripped of the unused QKV epilogues.
// 512 blocks = 2/CU resident (the supply-rate concurrency gemm128 always had).
__global__ __launch_bounds__(256) void gemm128p(
    const unsigned short* __restrict__ A,    // about [8192][1024] bf16
    const unsigned short* __restrict__ Bt,   // Pt [1024][1024] (row = out col)
    const float* __restrict__ bias,
    float* __restrict__ out_f)
{
    __shared__ unsigned short smem[16384];    // 32 KB staging
    unsigned short (*As)[64] = (unsigned short (*)[64])(smem);
    unsigned short (*Bs)[64] = (unsigned short (*)[64])(smem + 8192);

    const int tid  = threadIdx.x;
    const int w    = tid >> 6;
    const int lane = tid & 63;

    // XCD-aware 2-D supertile swizzle (nx=8): 512 = 8 XCD x 64
    const int n    = blockIdx.x;
    const int xcd  = n & 7;
    const int sgrp = n >> 3;
    const int m0   = ((xcd >> 1) * 16 + sgrp / 4) * 128;
    const int n0   = ((xcd & 1) * 4 + sgrp % 4) * 128;

    const int wm   = (w >> 1) * 64;
    const int wn   = (w & 1) * 64;
    const int lrow = lane & 15;
    const int quad = lane >> 4;

    f32x4 acc[4][4] = {};

    // staging: wave w covers rows [w*32, w*32+32) in 4 calls of 8 rows each.
    const int rr   = lane >> 3;
    const int scol = (((lane & 7) ^ (lane >> 3)) << 3);
    const unsigned short* Ag = A  + (size_t)(m0 + w * 32 + rr) * 1024 + scol;
    const unsigned short* Bg = Bt + (size_t)(n0 + w * 32 + rr) * 1024 + scol;
    unsigned short* ldsA = smem + (w * 32) * 64;
    unsigned short* ldsB = smem + 8192 + (w * 32) * 64;

    const int swz = lrow & 7;                 // fragment-read swizzle

    for (int k0 = 0; k0 < 1024; k0 += 64) {
        __syncthreads();
#pragma unroll
        for (int c = 0; c < 4; ++c) {
            load_lds16(Ag + (size_t)(c * 8) * 1024 + k0, ldsA + c * 512);
            load_lds16(Bg + (size_t)(c * 8) * 1024 + k0, ldsB + c * 512);
        }
        __syncthreads();
#pragma unroll
        for (int kk = 0; kk < 2; ++kk) {
            bf16x8 af[4], bfr[4];
            const int pc = (((kk * 4 + quad) ^ swz) << 3);
#pragma unroll
            for (int i = 0; i < 4; ++i) {
                af[i]  = *(const bf16x8*)&As[wm + i * 16 + lrow][pc];
                bfr[i] = *(const bf16x8*)&Bs[wn + i * 16 + lrow][pc];
            }
#pragma unroll
            for (int i = 0; i < 4; ++i)
#pragma unroll
                for (int j = 0; j < 4; ++j)
                    acc[i][j] = __builtin_amdgcn_mfma_f32_16x16x32_bf16(af[i], bfr[j], acc[i][j], 0, 0, 0);
        }
    }

    // direct fp32 epilogue (verified mode-1 algebra)
#pragma unroll
    for (int i = 0; i < 4; ++i)
#pragma unroll
        for (int j = 0; j < 4; ++j) {
            const int ncol = n0 + wn + j * 16 + lrow;
            const float bv = bias[ncol];
#pragma unroll
            for (int r = 0; r < 4; ++r) {
                const int mrow = m0 + wm + i * 16 + quad * 4 + r;
                out_f[(size_t)mrow * NXx + ncol] = acc[i][j][r] + bv;
            }
        }
}

// ---------------- flash-style causal attention, S^T, 8-wave 256-row supertiles ----------------
// r8-measured version (two-barrier, triple-buffer depth-2, vmcnt(4)/2/0).
// Qh pre-scaled by 0.125 in QKV epilogue; P packing via v_cvt_pk_bf16_f32.
__global__ __launch_bounds__(512) void flash_attn(
    const unsigned short* __restrict__ Qh,
    const unsigned short* __restrict__ Kh,
    const unsigned short* __restrict__ Vt,
    unsigned short* __restrict__ about)
{
    __shared__ unsigned short Ks[3][64][64];     // phys_chunk = log ^ (row&7)
    __shared__ unsigned short Vs[3][64][64];
    __shared__ unsigned short Pl[8][32][72];     // per-wave P, [q][key], stride 144B

    const int tid  = threadIdx.x;
    const int w    = tid >> 6;                   // 0..7
    const int lane = tid & 63;
    const int bh   = blockIdx.x & 127;
    const int prg  = blockIdx.x >> 7;            // 0 -> (st 0,3), 1 -> (st 1,2)
    const int b    = bh >> 4, h = bh & 15;
    const int lrow = lane & 15;
    const int quad = lane >> 4;

    const unsigned short* Qb = Qh + (size_t)bh * Ss * HDd;
    const unsigned short* Kb = Kh + (size_t)bh * Ss * HDd;
    const unsigned short* Vb = Vt + (size_t)bh * HDd * Ss;

    const int sr = lane >> 3;
    const int lc = (((lane & 7) ^ sr) << 3);

    const int swz = lrow & 7;
    const int ca = ((quad ^ swz) << 3);            // k/d 0..31
    const int cb = (((4 + quad) ^ swz) << 3);      // k/d 32..63

    const int nkt0 = 4 * prg + 4;                  // half-A iters; total = 20
    int qw = prg * 256 + w * 32;                   // wave's first q row

    bf16x8 aq[2][2];
#pragma unroll
    for (int g = 0; g < 2; ++g)
#pragma unroll
        for (int c = 0; c < 2; ++c)
            aq[g][c] = *(const bf16x8*)(Qb + (size_t)(qw + g * 16 + lrow) * HDd + c * 32 + quad * 8);

    f32x4 O[2][4] = {};
    float lsum[2] = { 0.f, 0.f };

    // prologue: stage iters 0,1 into bufs 0,1
#pragma unroll
    for (int p = 0; p < 2; ++p) {
        load_lds16(Kb + (size_t)(p * 64 + w * 8 + sr) * HDd + lc, &Ks[p][w * 8][0]);
        load_lds16(Vb + (size_t)(w * 8 + sr) * Ss + p * 64 + lc,  &Vs[p][w * 8][0]);
    }

    int cbuf = 0, sbuf = 2;
#pragma unroll 1
    for (int it = 0; it < 20; ++it) {
        __builtin_amdgcn_s_barrier();   // barA: all reads of sbuf (iter it-1) done
        asm volatile("" ::: "memory");
        if (it <= 17) {                 // stage iter it+2
            const int itn = it + 2;
            const int k0n = (itn >= nkt0 ? itn - nkt0 : itn) * 64;
            load_lds16(Kb + (size_t)(k0n + w * 8 + sr) * HDd + lc, &Ks[sbuf][w * 8][0]);
            load_lds16(Vb + (size_t)(w * 8 + sr) * Ss + k0n + lc,  &Vs[sbuf][w * 8][0]);
            asm volatile("s_waitcnt vmcnt(4)" ::: "memory");   // retire iter-it's 2
        } else if (it == 18) {
            asm volatile("s_waitcnt vmcnt(2)" ::: "memory");
        } else {
            asm volatile("s_waitcnt vmcnt(0)" ::: "memory");
        }
        __builtin_amdgcn_s_barrier();   // barB: everyone's iter-it staging retired
        asm volatile("" ::: "memory");

        if (it == nkt0) {
            // finish half A: quad-reduce l, normalize, store (registers + shfl only)
#pragma unroll
            for (int g = 0; g < 2; ++g) {
                float l = lsum[g];
                l += __shfl_xor(l, 16);
                l += __shfl_xor(l, 32);
                const float inv = 1.0f / l;
#pragma unroll
                for (int r = 0; r < 4; ++r) {
                    const float invr = __shfl(inv, quad * 4 + r);
                    const int q = qw + g * 16 + quad * 4 + r;
                    const size_t base = ((size_t)b * Ss + q) * NXx + h * HDd;
#pragma unroll
                    for (int f = 0; f < 4; ++f)
                        about[base + f * 16 + lrow] = f2bf(O[g][f][r] * invr);
                }
            }
            // switch to half B (supertile 3-prg)
            qw = (3 - prg) * 256 + w * 32;
#pragma unroll
            for (int g = 0; g < 2; ++g)
#pragma unroll
                for (int c = 0; c < 2; ++c)
                    aq[g][c] = *(const bf16x8*)(Qb + (size_t)(qw + g * 16 + lrow) * HDd + c * 32 + quad * 8);
#pragma unroll
            for (int g = 0; g < 2; ++g) {
                lsum[g] = 0.f;
#pragma unroll
                for (int f = 0; f < 4; ++f) O[g][f] = (f32x4){0.f, 0.f, 0.f, 0.f};
            }
        }

        const int k0 = (it >= nkt0 ? it - nkt0 : it) * 64;
        if (k0 <= qw + 31) {                   // else fully masked (wave-uniform)
            // S^T = K·Q^T: D[key = j*16+quad*4+r][q = g*16+lrow]
            f32x4 st[2][4] = {};
#pragma unroll
            for (int j = 0; j < 4; ++j) {
                const bf16x8 kf0 = *(const bf16x8*)&Ks[cbuf][j * 16 + lrow][ca];
                const bf16x8 kf1 = *(const bf16x8*)&Ks[cbuf][j * 16 + lrow][cb];
                st[0][j] = __builtin_amdgcn_mfma_f32_16x16x32_bf16(kf0, aq[0][0], st[0][j], 0, 0, 0);
                st[0][j] = __builtin_amdgcn_mfma_f32_16x16x32_bf16(kf1, aq[0][1], st[0][j], 0, 0, 0);
                st[1][j] = __builtin_amdgcn_mfma_f32_16x16x32_bf16(kf0, aq[1][0], st[1][j], 0, 0, 0);
                st[1][j] = __builtin_amdgcn_mfma_f32_16x16x32_bf16(kf1, aq[1][1], st[1][j], 0, 0, 0);
            }

            const bool needMask = (k0 + 63 > qw);  // wave-uniform
#pragma unroll
            for (int g = 0; g < 2; ++g) {
                const int qg = qw + g * 16 + lrow;  // this lane's q row
#pragma unroll
                for (int j = 0; j < 4; ++j) {
                    const int kbase = k0 + j * 16 + quad * 4;
                    float e0 = __expf(st[g][j][0]);   // Qh pre-scaled by 0.125
                    float e1 = __expf(st[g][j][1]);
                    float e2 = __expf(st[g][j][2]);
                    float e3 = __expf(st[g][j][3]);
                    if (needMask) {
                        if (kbase     > qg) e0 = 0.f;
                        if (kbase + 1 > qg) e1 = 0.f;
                        if (kbase + 2 > qg) e2 = 0.f;
                        if (kbase + 3 > qg) e3 = 0.f;
                    }
                    lsum[g] += (e0 + e1) + (e2 + e3);
                    uint2 pk;
                    pk.x = cvt_pk_bf16(e0, e1);
                    pk.y = cvt_pk_bf16(e2, e3);
                    *(uint2*)&Pl[w][g * 16 + lrow][j * 16 + quad * 4] = pk;
                }
            }
            // Pl[w] is per-wave: in-wave DS ordering suffices, no barrier

            bf16x8 ap[2][2];
#pragma unroll
            for (int g = 0; g < 2; ++g)
#pragma unroll
                for (int c = 0; c < 2; ++c)
                    ap[g][c] = *(const bf16x8*)&Pl[w][g * 16 + lrow][c * 32 + quad * 8];
#pragma unroll
            for (int f = 0; f < 4; ++f) {
                const bf16x8 vf0 = *(const bf16x8*)&Vs[cbuf][f * 16 + lrow][ca];
                const bf16x8 vf1 = *(const bf16x8*)&Vs[cbuf][f * 16 + lrow][cb];
                O[0][f] = __builtin_amdgcn_mfma_f32_16x16x32_bf16(ap[0][0], vf0, O[0][f], 0, 0, 0);
                O[0][f] = __builtin_amdgcn_mfma_f32_16x16x32_bf16(ap[0][1], vf1, O[0][f], 0, 0, 0);
                O[1][f] = __builtin_amdgcn_mfma_f32_16x16x32_bf16(ap[1][0], vf0, O[1][f], 0, 0, 0);
                O[1][f] = __builtin_amdgcn_mfma_f32_16x16x32_bf16(ap[1][1], vf1, O[1][f], 0, 0, 0);
            }
        }

        cbuf = (cbuf == 2) ? 0 : cbuf + 1;
        sbuf = (sbuf == 2) ? 0 : sbuf + 1;
    }

    // final epilogue: half B
#pragma unroll
    for (int g = 0; g < 2; ++g) {
        float l = lsum[g];
        l += __shfl_xor(l, 16);
        l += __shfl_xor(l, 32);
        const float inv = 1.0f / l;
#pragma unroll
        for (int r = 0; r < 4; ++r) {
            const float invr = __shfl(inv, quad * 4 + r);
            const int q = qw + g * 16 + quad * 4 + r;
            const size_t base = ((size_t)b * Ss + q) * NXx + h * HDd;
#pragma unroll
            for (int f = 0; f < 4; ++f)
                about[base + f * 16 + lrow] = f2bf(O[g][f][r] * invr);
        }
    }
}

// ---------------- launch ----------------
extern "C" void kernel_launch(void* const* d_in, const int* in_sizes, int n_in,
                              void* d_out, int out_size, void* d_ws, size_t ws_size,
                              hipStream_t stream) {
    const float* x        = (const float*)d_in[0];
    const float* query    = (const float*)d_in[1];
    const float* c_attn_w = (const float*)d_in[2];
    const float* c_attn_b = (const float*)d_in[3];
    const float* c_proj_w = (const float*)d_in[4];
    const float* c_proj_b = (const float*)d_in[5];
    float* out = (float*)d_out;

    const size_t nTok = (size_t)Mm * NXx;          // 8388608
    char* ws = (char*)d_ws;
    unsigned short* xb    = (unsigned short*)ws;                 ws += nTok * 2;
    unsigned short* qb    = (unsigned short*)ws;                 ws += nTok * 2;
    unsigned short* Wt    = (unsigned short*)ws;                 ws += (size_t)3 * NXx * NXx * 2;  // [3072][1024]
    unsigned short* Pt    = (unsigned short*)ws;                 ws += (size_t)NXx * NXx * 2;      // [1024][1024]
    unsigned short* Qh    = (unsigned short*)ws;                 ws += nTok * 2;
    unsigned short* Kh    = (unsigned short*)ws;                 ws += nTok * 2;
    unsigned short* Vt    = (unsigned short*)ws;                 ws += nTok * 2;
    unsigned short* about = (unsigned short*)ws;                 ws += nTok * 2;
    if ((size_t)(ws - (char*)d_ws) > ws_size) return;

    // merged prep: casts + transposes
    prep<<<20480, 256, 0, stream>>>(x, query, c_attn_w, c_proj_w, xb, qb, Wt, Pt);

    // QKV: M=8192, N=3072, K=1024 — single-barrier ring (r9-measured best: 63.2us)
    gemm256<<<768, 512, 0, stream>>>(xb, qb, Wt, c_attn_b, Qh, Kh, Vt);

    // causal flash attention (r8-measured two-barrier version)
    flash_attn<<<256, 512, 0, stream>>>(Qh, Kh, Vt, about);

    // output projection (r8-measured gemm128 structure, proj-only)
    gemm128p<<<512, 256, 0, stream>>>(about, Pt, c_proj_b, out);
}